// Round 15
// baseline (65.190 us; speedup 1.0000x reference)
//
#include <hip/hip_runtime.h>
#include <hip/hip_bf16.h>
#include <hip/hip_fp16.h>

// Problem constants (B=4, C=256, H=W=64, hs=ws=32, rate=2, vk=4, pad=1)
#define BB 4
#define CC 256
#define HH 64
#define WW 64
#define QRN 1024
#define KN  1024
#define KDIM 1152            // 33*33 = 1089 padded to 36*32
#define TROWS 1089           // 33*33 combined-score rows per b

typedef _Float16 f16x8 __attribute__((ext_vector_type(8)));
typedef float f32x16 __attribute__((ext_vector_type(16)));

#define TP_ELEMS ((size_t)BB * TROWS * KDIM)   // 5,018,112 halves (10.0 MB)
#define BP_ELEMS ((size_t)16 * CC * KDIM)      // 4,718,592 halves (9.4 MB)

// ===========================================================================
// FAST PATH
// ===========================================================================

// One qr row of the combined-score tensor T (all 1152 k, 5 chunks/thread).
// T[b][qr=Qa*33+Ra][k=(mp,np)] =
//   sum_{dq,dr in {0,1}} [masks] s[b][(Qa-dq)*32+(Ra-dr)][(mp-dq)*32+(np-dr)]
// Pad region k>=1089 -> all masks false -> 0 (required: gemm multiplies it).
__device__ __forceinline__
void process_qr(const float* __restrict__ sb, _Float16* __restrict__ T,
                int b, int qr, int t) {
    const int Qa = (qr * 993) >> 15;        // qr/33 (exact for qr<2048)
    const int Ra = qr - 33 * Qa;
    const bool q0 = (Qa < 32), q1 = (Qa >= 1);        // block-uniform
    const bool r0 = (Ra < 32), r1 = (Ra >= 1);        // block-uniform
    const float* rb00 = sb + ((size_t)((Qa)     * 32 + (Ra)))     * KN;
    const float* rb01 = sb + ((size_t)((Qa)     * 32 + (Ra - 1))) * KN;
    const float* rb10 = sb + ((size_t)((Qa - 1) * 32 + (Ra)))     * KN;
    const float* rb11 = sb + ((size_t)((Qa - 1) * 32 + (Ra - 1))) * KN;
    _Float16* trow = T + ((size_t)b * TROWS + qr) * KDIM;

    float v[5];
    #pragma unroll
    for (int j = 0; j < 5; ++j) {
        const int k = j * 256 + t;
        v[j] = 0.f;
        if (k < KDIM) {
            const int mp = (k * 993) >> 15;  // k/33 (exact for k<2048)
            const int np = k - 33 * mp;
            const bool m0 = (mp < 32), m1 = (mp >= 1) && (mp < 33);
            const bool n0 = (np < 32), n1 = (np >= 1);
            const int col = (mp << 5) + np;
            if (q0 & r0 & m0 & n0) v[j] += rb00[col];
            if (q0 & r1 & m0 & n1) v[j] += rb01[col - 1];
            if (q1 & r0 & m1 & n0) v[j] += rb10[col - 32];
            if (q1 & r1 & m1 & n1) v[j] += rb11[col - 33];
        }
    }
    #pragma unroll
    for (int j = 0; j < 5; ++j) {
        const int k = j * 256 + t;
        if (k < KDIM) trow[k] = (_Float16)v[j];
    }
}

// Merged builder: T part (2 qr rows per block) + B part (x gather).
// Bijective XCD-chunk swizzle keeps all shifted readers of each scores
// element on one XCD's L2.
#define T_BLOCKS 545
#define PER_B    705
#define TB_NWG   (BB * PER_B)    // 2820

__global__ __launch_bounds__(256)
void build_TB(const float* __restrict__ s, const float* __restrict__ x,
              _Float16* __restrict__ T, _Float16* __restrict__ Bp) {
    // bijective XCD chunk remap (m204 form; nwg % 8 = 4)
    const int orig = blockIdx.x;
    const int xcd = orig & 7, pos = orig >> 3;
    const int q = TB_NWG / 8, r = TB_NWG % 8;            // 352, 4
    const int wgid =
        (xcd < r ? xcd * (q + 1) : r * (q + 1) + (xcd - r) * q) + pos;

    const int b = wgid / PER_B;
    const int rem = wgid - b * PER_B;
    const int t = threadIdx.x;

    if (rem < T_BLOCKS) {
        const float* sb = s + (size_t)b * QRN * KN;
        const int qr0 = rem * 2;
        process_qr(sb, T, b, qr0, t);
        if (qr0 + 1 < TROWS) process_qr(sb, T, b, qr0 + 1, t);
    } else {
        // ---------------- B part: Bp[bc][c][k] = gathered x ---------------
        const int u = rem - T_BLOCKS;           // [0,160)
        const int rest = u / 5;
        const int kc = u - rest * 5;
        const int cls = rest >> 3, cg = rest & 7;
        const int k = kc * 256 + t;
        if (k >= KDIM) return;
        const int ph = cls >> 1, pw = cls & 1;
        const int ua = 1 - ph, va = 1 - pw;
        const int bc = b * 4 + cls;

        const int mp = (k * 993) >> 15;
        const int np = k - 33 * mp;
        int rr = 2 * mp + ua - 1; rr = min(max(rr, 0), HH - 1);
        int cc2 = 2 * np + va - 1; cc2 = min(max(cc2, 0), WW - 1);
        const int off = rr * WW + cc2;

        const float* xb = x + ((size_t)b * CC + cg * 32) * HH * WW;
        _Float16* bpb = Bp + ((size_t)bc * CC + cg * 32) * KDIM + k;

        #pragma unroll 8
        for (int i = 0; i < 32; ++i) {
            bpb[(size_t)i * KDIM] = (_Float16)xb[(size_t)i * HH * WW + off];
        }
    }
}

// Direct global->LDS DMA (16 B per lane).  LDS dest is wave-uniform base +
// lane*16; our chunk order is exactly thread order, so dest = per-lane addr.
__device__ __forceinline__ void gload16(const _Float16* g, _Float16* l) {
    __builtin_amdgcn_global_load_lds(
        (const __attribute__((address_space(1))) unsigned int*)g,
        (__attribute__((address_space(3))) unsigned int*)l, 16, 0, 0);
}

// GEMM per (b,class): D[c][px] = sum_k Bp[c][k] * T[b][trow(px,cls)][k]
// Tile 64(c) x 128(px), 512 blocks (2/CU). 4 waves = 2(n-half) x 2(k-slice).
// BK=32, 36 steps. T3/T4: global_load_lds staging (3 DMA/thread/step) into a
// 4-deep LDS buffer ring (4 x 12 KB, slot-major = DMA-linear AND
// conflict-free b128 reads), counted s_waitcnt vmcnt(6) - never drained to 0
// in the loop - one barrier per step, no ds_writes, no register ring.
// Tail steps re-issue the last stage set (identical bytes - benign race).
// After K-loop: k-slices reduced across wave pairs via LDS; ks=0 waves do
// the epilogue out = ori_x + 0.25*alpha*D (each output pixel exactly once).
#define NSTEP  36                // KDIM/32
#define ABUF_H 2048              // halves per A buffer: [4 slots][64 rows][8]
#define BBUF_H 4096              // halves per B buffer: [4 slots][128 rows][8]
#define B_BASE 8192              // halves offset of B buffers (after 4 A bufs)
__global__ __launch_bounds__(256)
void gemm_f16(const _Float16* __restrict__ T,    // [4][1089][1152] (px side)
              const _Float16* __restrict__ Bp,   // [16][256][1152] (c side)
              const float* __restrict__ orix,
              const float* __restrict__ alphap,
              float* __restrict__ out) {
    __shared__ __align__(16) _Float16 smem_h[24576];   // 48 KB
    float* ex = (float*)smem_h;                        // reduction overlay

    // XCD-grouping remap: XCD r gets 64 consecutive wids = 2 bc panels
    const int lin = blockIdx.x + 4 * (blockIdx.y + 8 * blockIdx.z); // 0..511
    const int wid = (lin & 7) * 64 + (lin >> 3);
    const int bc  = wid >> 5;
    const int byy = (wid >> 2) & 7;
    const int bxx = wid & 3;

    const int b = bc >> 2, cls = bc & 3;
    const int ph = cls >> 1, pw = cls & 1;
    const int c0  = bxx * 64;
    const int px0 = byy * 128;

    const int t = threadIdx.x;
    const int w = t >> 6, l = t & 63;
    const int lr = l & 31;                // row within 32-tile
    const int lh = l >> 5;                // k-half (8-k granule) selector
    const int wc = w & 1;                 // n-half (which 64 of 128 px)
    const int ks = w >> 1;                // k-slice (which 16 of BK=32)

    const _Float16* Ag = Bp + ((size_t)bc * CC + c0) * KDIM;   // M operand
    const _Float16* Tg = T + (size_t)b * TROWS * KDIM;         // N operand

    // Staging map (chunk id == thread id -> LDS linear):
    //   A: slot = w, row = l           (1 chunk/thread)
    //   B: slot = (w>>1)+2i, row = (w&1)*64 + l   (i = 0,1)
    const int rowB = (w & 1) * 64 + l;
    const int pxB = px0 + rowB;
    const int trowB = ((pxB >> 5) + ph) * 33 + (pxB & 31) + pw;

    const _Float16* srcA = Ag + (size_t)l * KDIM + w * 8;
    const _Float16* srcB = Tg + (size_t)trowB * KDIM + (w >> 1) * 8;
    _Float16* dstA = smem_h + w * 512 + l * 8;
    _Float16* dstB = smem_h + B_BASE + w * 512 + l * 8;

    #define ISSUE(ts2)                                                     \
        do {                                                               \
            const int _bf = (ts2) & 3;                                     \
            const int _k0 = (ts2) * 32;                                    \
            gload16(srcA + _k0, dstA + _bf * ABUF_H);                      \
            gload16(srcB + _k0, dstB + _bf * BBUF_H);                      \
            gload16(srcB + _k0 + 16, dstB + _bf * BBUF_H + 2048);          \
        } while (0)

    f32x16 acc[2][2];
    #pragma unroll
    for (int i = 0; i < 2; ++i)
        #pragma unroll
        for (int j = 0; j < 2; ++j)
            acc[i][j] = (f32x16)(0.f);

    // prologue: fill buffers 0,1,2 (9 DMA in flight)
    ISSUE(0); ISSUE(1); ISSUE(2);

    for (int ts = 0; ts < NSTEP; ++ts) {
        // S(ts) is the oldest of <=9 outstanding DMAs -> vmcnt(6) retires it
        asm volatile("s_waitcnt vmcnt(6)" ::: "memory");
        __builtin_amdgcn_s_barrier();
        // refill the buffer freed at step ts-1 (readers separated by barrier)
        const int nxt = (ts + 3 < NSTEP) ? ts + 3 : NSTEP - 1;
        ISSUE(nxt);

        const int bufb = ts & 3;
        const _Float16* ab = smem_h + bufb * ABUF_H;
        const _Float16* bb = smem_h + B_BASE + bufb * BBUF_H;
        const int slot = ks * 2 + lh;
        f16x8 af0 = *(const f16x8*)(ab + slot * 512 + lr * 8);
        f16x8 af1 = *(const f16x8*)(ab + slot * 512 + (32 + lr) * 8);
        f16x8 bf0 = *(const f16x8*)(bb + slot * 1024 + (wc * 64 + lr) * 8);
        f16x8 bf1 = *(const f16x8*)(bb + slot * 1024 + (wc * 64 + 32 + lr) * 8);
        __builtin_amdgcn_s_setprio(1);
        acc[0][0] = __builtin_amdgcn_mfma_f32_32x32x16_f16(af0, bf0, acc[0][0], 0, 0, 0);
        acc[0][1] = __builtin_amdgcn_mfma_f32_32x32x16_f16(af0, bf1, acc[0][1], 0, 0, 0);
        acc[1][0] = __builtin_amdgcn_mfma_f32_32x32x16_f16(af1, bf0, acc[1][0], 0, 0, 0);
        acc[1][1] = __builtin_amdgcn_mfma_f32_32x32x16_f16(af1, bf1, acc[1][1], 0, 0, 0);
        __builtin_amdgcn_s_setprio(0);
    }
    #undef ISSUE

    // drain all DMA before overlaying ex on the staging buffers
    asm volatile("s_waitcnt vmcnt(0) lgkmcnt(0)" ::: "memory");
    __builtin_amdgcn_s_barrier();

    // ---- cross-wave k-slice reduction: ks=1 waves dump, ks=0 waves add.
    if (ks == 1) {
        #pragma unroll
        for (int mt = 0; mt < 2; ++mt)
            #pragma unroll
            for (int nt2 = 0; nt2 < 2; ++nt2)
                #pragma unroll
                for (int r2 = 0; r2 < 16; ++r2)
                    ex[((((mt * 2 + nt2) * 2 + wc) * 16) + r2) * 64 + l] =
                        acc[mt][nt2][r2];
    }
    asm volatile("s_waitcnt lgkmcnt(0)" ::: "memory");
    __builtin_amdgcn_s_barrier();

    if (ks == 0) {
        const float scale = 0.25f * alphap[0];
        #pragma unroll
        for (int mt = 0; mt < 2; ++mt) {
            #pragma unroll
            for (int nt2 = 0; nt2 < 2; ++nt2) {
                #pragma unroll
                for (int r2 = 0; r2 < 16; ++r2) {
                    float vsum = acc[mt][nt2][r2] +
                        ex[((((mt * 2 + nt2) * 2 + wc) * 16) + r2) * 64 + l];
                    int c  = c0 + mt * 32 + (r2 & 3) + 8 * (r2 >> 2) + 4 * lh;
                    int px = px0 + wc * 64 + nt2 * 32 + lr;
                    int hh = px >> 5, ww2 = px & 31;
                    int h = 2 * hh + ph, wp = 2 * ww2 + pw;
                    size_t idx = (((size_t)b * CC + c) * HH + h) * WW + wp;
                    out[idx] = orix[idx] + scale * vsum;
                }
            }
        }
    }
}

// ===========================================================================
// FALLBACK PATH (round-1 kernels, used only if ws too small)
// ===========================================================================
#define TILE_M 64
#define TILE_N 64
#define TILE_K 16

__global__ void copy_kernel(const float* __restrict__ src,
                            float* __restrict__ dst, int n4) {
    int i = blockIdx.x * blockDim.x + threadIdx.x;
    if (i < n4)
        reinterpret_cast<float4*>(dst)[i] =
            reinterpret_cast<const float4*>(src)[i];
}

__global__ void transpose_kernel(const float* __restrict__ x,
                                 float* __restrict__ xT) {
    __shared__ float tile[32][33];
    int bh = blockIdx.z;
    int b = bh >> 6, h = bh & 63;
    int c0 = blockIdx.y * 32, w0 = blockIdx.x * 32;
    int tw = threadIdx.x & 31;
    int tc = threadIdx.x >> 5;
    #pragma unroll
    for (int i = 0; i < 4; ++i) {
        int c = tc + i * 8;
        tile[c][tw] = x[(((size_t)b * CC + c0 + c) * HH + h) * WW + w0 + tw];
    }
    __syncthreads();
    int tcw = threadIdx.x & 31;
    int twr = threadIdx.x >> 5;
    #pragma unroll
    for (int i = 0; i < 4; ++i) {
        int w = twr + i * 8;
        xT[(((size_t)b * HH + h) * WW + w0 + w) * CC + c0 + tcw] = tile[tcw][w];
    }
}

__global__ __launch_bounds__(256)
void pgemm_scatter(const float* __restrict__ scores,
                   const float* __restrict__ xT,
                   const float* __restrict__ x,
                   const float* __restrict__ alpha,
                   float* __restrict__ out,
                   int use_xt) {
    __shared__ float As[TILE_K][TILE_M];
    __shared__ float Bs[TILE_K][TILE_N];

    const int b      = blockIdx.z;
    const int tile_n = blockIdx.x;
    const int m0     = blockIdx.y * TILE_M;
    const int uv     = tile_n >> 2;
    const int u      = uv >> 2, v = uv & 3;
    const int c0     = (tile_n & 3) * 64;

    const int t  = threadIdx.x;
    const int tx = t & 15;
    const int ty = t >> 4;

    float acc[4][4] = {};
    const float* sb = scores + (size_t)b * QRN * KN;

    for (int k0 = 0; k0 < KN; k0 += TILE_K) {
        {
            int mr = t >> 2;
            int kc = (t & 3) * 4;
            float4 av = *reinterpret_cast<const float4*>(
                sb + (size_t)(m0 + mr) * KN + k0 + kc);
            As[kc + 0][mr] = av.x;
            As[kc + 1][mr] = av.y;
            As[kc + 2][mr] = av.z;
            As[kc + 3][mr] = av.w;
        }
        {
            int kr = t >> 4;
            int kg = k0 + kr;
            int m  = kg >> 5, n = kg & 31;
            int rr = 2 * m + u - 1; rr = min(max(rr, 0), HH - 1);
            int cc = 2 * n + v - 1; cc = min(max(cc, 0), WW - 1);
            int ccol = (t & 15) * 4;
            if (use_xt) {
                float4 bv = *reinterpret_cast<const float4*>(
                    xT + ((((size_t)b * HH + rr) * WW + cc) * CC) + c0 + ccol);
                Bs[kr][ccol + 0] = bv.x;
                Bs[kr][ccol + 1] = bv.y;
                Bs[kr][ccol + 2] = bv.z;
                Bs[kr][ccol + 3] = bv.w;
            } else {
                #pragma unroll
                for (int j = 0; j < 4; ++j) {
                    int c = c0 + ccol + j;
                    Bs[kr][ccol + j] =
                        x[(((size_t)b * CC + c) * HH + rr) * WW + cc];
                }
            }
        }
        __syncthreads();

        #pragma unroll
        for (int k = 0; k < TILE_K; ++k) {
            float a4[4], b4[4];
            *reinterpret_cast<float4*>(a4) =
                *reinterpret_cast<const float4*>(&As[k][ty * 4]);
            *reinterpret_cast<float4*>(b4) =
                *reinterpret_cast<const float4*>(&Bs[k][tx * 4]);
            #pragma unroll
            for (int i = 0; i < 4; ++i)
                #pragma unroll
                for (int j = 0; j < 4; ++j)
                    acc[i][j] += a4[i] * b4[j];
        }
        __syncthreads();
    }

    const float scale = alpha[0] * 0.25f;
    #pragma unroll
    for (int i = 0; i < 4; ++i) {
        int qr = m0 + ty * 4 + i;
        int Q = qr >> 5, R = qr & 31;
        int h = 2 * Q + u - 1;
        int w = 2 * R + v - 1;
        if (h < 0 || h >= HH || w < 0 || w >= WW) continue;
        #pragma unroll
        for (int j = 0; j < 4; ++j) {
            int c = c0 + tx * 4 + j;
            atomicAdd(&out[(((size_t)b * CC + c) * HH + h) * WW + w],
                      acc[i][j] * scale);
        }
    }
}

// ===========================================================================
extern "C" void kernel_launch(void* const* d_in, const int* in_sizes, int n_in,
                              void* d_out, int out_size, void* d_ws,
                              size_t ws_size, hipStream_t stream) {
    const float* ori_x  = (const float*)d_in[0];
    const float* scores = (const float*)d_in[1];
    const float* alpha  = (const float*)d_in[2];
    float* out = (float*)d_out;

    const size_t need_fast = (TP_ELEMS + BP_ELEMS) * sizeof(_Float16);

    if (ws_size >= need_fast) {
        _Float16* T  = (_Float16*)d_ws;
        _Float16* Bp = T + TP_ELEMS;

        build_TB<<<dim3(TB_NWG), 256, 0, stream>>>(scores, ori_x, T, Bp);
        gemm_f16<<<dim3(4, 8, 16), 256, 0, stream>>>(T, Bp, ori_x, alpha, out);
    } else {
        float* xT = (float*)d_ws;
        const size_t xt_bytes = (size_t)BB * HH * WW * CC * sizeof(float);
        const int use_xt = (ws_size >= xt_bytes) ? 1 : 0;

        copy_kernel<<<(BB * CC * HH * WW / 4 + 255) / 256, 256, 0, stream>>>(
            ori_x, out, BB * CC * HH * WW / 4);
        if (use_xt)
            transpose_kernel<<<dim3(WW / 32, CC / 32, BB * HH), 256, 0,
                               stream>>>(ori_x, xT);
        pgemm_scatter<<<dim3(16, 16, BB), 256, 0, stream>>>(
            scores, xT, ori_x, alpha, out, use_xt);
    }
}

// Round 16
// 46.543 us; speedup vs baseline: 1.4006x; 1.4006x over previous
//
#include <hip/hip_runtime.h>
#include <hip/hip_bf16.h>
#include <hip/hip_fp16.h>

// Problem constants (B=4, C=256, H=W=64, hs=ws=32, rate=2, vk=4, pad=1)
#define BB 4
#define CC 256
#define HH 64
#define WW 64
#define QRN 1024
#define KN  1024
#define KDIM 1152            // 33*33 = 1089 padded to 36*32
#define TROWS 1089           // 33*33 combined-score rows per b

typedef _Float16 f16x8 __attribute__((ext_vector_type(8)));
typedef float f32x4 __attribute__((ext_vector_type(4)));

#define TP_ELEMS ((size_t)BB * TROWS * KDIM)   // 5,018,112 halves (10.0 MB)
#define BP_ELEMS ((size_t)16 * CC * KDIM)      // 4,718,592 halves (9.4 MB)

// ===========================================================================
// FAST PATH
// ===========================================================================

// One qr row of the combined-score tensor T (all 1152 k, 5 chunks/thread).
// T[b][qr=Qa*33+Ra][k=(mp,np)] =
//   sum_{dq,dr in {0,1}} [masks] s[b][(Qa-dq)*32+(Ra-dr)][(mp-dq)*32+(np-dr)]
// Pad region k>=1089 -> all masks false -> 0 (required: gemm multiplies it).
__device__ __forceinline__
void process_qr(const float* __restrict__ sb, _Float16* __restrict__ T,
                int b, int qr, int t) {
    const int Qa = (qr * 993) >> 15;        // qr/33 (exact for qr<2048)
    const int Ra = qr - 33 * Qa;
    const bool q0 = (Qa < 32), q1 = (Qa >= 1);        // block-uniform
    const bool r0 = (Ra < 32), r1 = (Ra >= 1);        // block-uniform
    const float* rb00 = sb + ((size_t)((Qa)     * 32 + (Ra)))     * KN;
    const float* rb01 = sb + ((size_t)((Qa)     * 32 + (Ra - 1))) * KN;
    const float* rb10 = sb + ((size_t)((Qa - 1) * 32 + (Ra)))     * KN;
    const float* rb11 = sb + ((size_t)((Qa - 1) * 32 + (Ra - 1))) * KN;
    _Float16* trow = T + ((size_t)b * TROWS + qr) * KDIM;

    float v[5];
    #pragma unroll
    for (int j = 0; j < 5; ++j) {
        const int k = j * 256 + t;
        v[j] = 0.f;
        if (k < KDIM) {
            const int mp = (k * 993) >> 15;  // k/33 (exact for k<2048)
            const int np = k - 33 * mp;
            const bool m0 = (mp < 32), m1 = (mp >= 1) && (mp < 33);
            const bool n0 = (np < 32), n1 = (np >= 1);
            const int col = (mp << 5) + np;
            if (q0 & r0 & m0 & n0) v[j] += rb00[col];
            if (q0 & r1 & m0 & n1) v[j] += rb01[col - 1];
            if (q1 & r0 & m1 & n0) v[j] += rb10[col - 32];
            if (q1 & r1 & m1 & n1) v[j] += rb11[col - 33];
        }
    }
    #pragma unroll
    for (int j = 0; j < 5; ++j) {
        const int k = j * 256 + t;
        if (k < KDIM) trow[k] = (_Float16)v[j];
    }
}

// Merged builder: T part (2 qr rows per block) + B part (x gather).
// Bijective XCD-chunk swizzle keeps all shifted readers of each scores
// element on one XCD's L2.
#define T_BLOCKS 545
#define PER_B    705
#define TB_NWG   (BB * PER_B)    // 2820

__global__ __launch_bounds__(256)
void build_TB(const float* __restrict__ s, const float* __restrict__ x,
              _Float16* __restrict__ T, _Float16* __restrict__ Bp) {
    // bijective XCD chunk remap (m204 form; nwg % 8 = 4)
    const int orig = blockIdx.x;
    const int xcd = orig & 7, pos = orig >> 3;
    const int q = TB_NWG / 8, r = TB_NWG % 8;            // 352, 4
    const int wgid =
        (xcd < r ? xcd * (q + 1) : r * (q + 1) + (xcd - r) * q) + pos;

    const int b = wgid / PER_B;
    const int rem = wgid - b * PER_B;
    const int t = threadIdx.x;

    if (rem < T_BLOCKS) {
        const float* sb = s + (size_t)b * QRN * KN;
        const int qr0 = rem * 2;
        process_qr(sb, T, b, qr0, t);
        if (qr0 + 1 < TROWS) process_qr(sb, T, b, qr0 + 1, t);
    } else {
        // ---------------- B part: Bp[bc][c][k] = gathered x ---------------
        const int u = rem - T_BLOCKS;           // [0,160)
        const int rest = u / 5;
        const int kc = u - rest * 5;
        const int cls = rest >> 3, cg = rest & 7;
        const int k = kc * 256 + t;
        if (k >= KDIM) return;
        const int ph = cls >> 1, pw = cls & 1;
        const int ua = 1 - ph, va = 1 - pw;
        const int bc = b * 4 + cls;

        const int mp = (k * 993) >> 15;
        const int np = k - 33 * mp;
        int rr = 2 * mp + ua - 1; rr = min(max(rr, 0), HH - 1);
        int cc2 = 2 * np + va - 1; cc2 = min(max(cc2, 0), WW - 1);
        const int off = rr * WW + cc2;

        const float* xb = x + ((size_t)b * CC + cg * 32) * HH * WW;
        _Float16* bpb = Bp + ((size_t)bc * CC + cg * 32) * KDIM + k;

        #pragma unroll 8
        for (int i = 0; i < 32; ++i) {
            bpb[(size_t)i * KDIM] = (_Float16)xb[(size_t)i * HH * WW + off];
        }
    }
}

// Direct global->LDS DMA (16 B per lane).
__device__ __forceinline__ void gload16(const _Float16* g, _Float16* l) {
    __builtin_amdgcn_global_load_lds(
        (const __attribute__((address_space(1))) unsigned int*)g,
        (__attribute__((address_space(3))) unsigned int*)l, 16, 0, 0);
}

// GEMM per (b,class): D[c][px] = sum_k Bp[c][k] * T[b][trow(px,cls)][k]
// m97 geometry: tile 128(c) x 128(px), 256 blocks (1/CU), 4 waves = 2x2
// quadrants of 64x64, NO k-split (each wave owns full K for its quadrant).
// BK=32, 36 steps, mfma_f32_16x16x32_f16: per wave-step 16 MFMA : 8
// ds_read_b128 (0.5 ratio). T3/T4: global_load_lds staging (4 DMA/thread/
// step) into a 4-deep LDS ring (4 x 16 KB, [row][32k] m97 layout =
// DMA-linear), counted s_waitcnt vmcnt(8) - never drained in the loop -
// one barrier per step, no ds_writes, no register staging, no reduction.
// Tail steps re-issue the last stage set (identical bytes - benign).
// Epilogue: out = ori_x + 0.25*alpha*D (each output pixel exactly once).
#define NSTEP  36                // KDIM/32
#define BUF_H  8192              // halves per ring buffer (A 4096 | B 4096)
__global__ __launch_bounds__(256, 1)
void gemm_f16(const _Float16* __restrict__ T,    // [4][1089][1152] (px side)
              const _Float16* __restrict__ Bp,   // [16][256][1152] (c side)
              const float* __restrict__ orix,
              const float* __restrict__ alphap,
              float* __restrict__ out) {
    __shared__ __align__(16) _Float16 smem_h[4 * BUF_H];   // 64 KB

    // XCD-grouping remap: XCD r gets 32 consecutive wids = 2 bc panels
    // (same b per XCD) -> T[b] + Bp panels stay L2-resident.
    const int lin = blockIdx.x + 2 * (blockIdx.y + 8 * blockIdx.z); // 0..255
    const int wid = (lin & 7) * 32 + (lin >> 3);
    const int bc  = wid >> 4;
    const int byy = (wid >> 1) & 7;
    const int bxx = wid & 1;

    const int b = bc >> 2, cls = bc & 3;
    const int ph = cls >> 1, pw = cls & 1;
    const int c0  = bxx * 128;
    const int px0 = byy * 128;

    const int t = threadIdx.x;
    const int wv = t >> 6, l = t & 63;
    const int lr = l & 15;                // 16x16 row/col within fragment
    const int lk = l >> 4;                // k-octet selector (8 halves)
    const int wr = wv >> 1, wc = wv & 1;  // wave quadrant (2x2 over 128x128)

    const _Float16* Ag = Bp + ((size_t)bc * CC + c0) * KDIM;   // M operand
    const _Float16* Tg = T + (size_t)b * TROWS * KDIM;         // N operand

    // Staging (chunk id == r*256+t; LDS halfoff = chunk*8 -> [row][32k]):
    //   row = chunk>>2 (r=0: 0..63, r=1: 64..127), slot = chunk&3.
    const int st_row = t >> 2, st_slot = t & 3;
    const _Float16* srcA0 = Ag + (size_t)st_row * KDIM + st_slot * 8;
    const _Float16* srcA1 = Ag + (size_t)(st_row + 64) * KDIM + st_slot * 8;
    const int pxr0 = px0 + st_row, pxr1 = px0 + st_row + 64;
    const int trow0 = ((pxr0 >> 5) + ph) * 33 + (pxr0 & 31) + pw;
    const int trow1 = ((pxr1 >> 5) + ph) * 33 + (pxr1 & 31) + pw;
    const _Float16* srcB0 = Tg + (size_t)trow0 * KDIM + st_slot * 8;
    const _Float16* srcB1 = Tg + (size_t)trow1 * KDIM + st_slot * 8;
    _Float16* dst0 = smem_h + t * 8;          // chunk r=0
    _Float16* dst1 = smem_h + 2048 + t * 8;   // chunk r=1
    // B region lives at +4096 halves within each buffer.

    #define ISSUE(ts2)                                                     \
        do {                                                               \
            const int _bo = ((ts2) & 3) * BUF_H;                           \
            const int _k0 = (ts2) * 32;                                    \
            gload16(srcA0 + _k0, dst0 + _bo);                              \
            gload16(srcA1 + _k0, dst1 + _bo);                              \
            gload16(srcB0 + _k0, dst0 + _bo + 4096);                       \
            gload16(srcB1 + _k0, dst1 + _bo + 4096);                       \
        } while (0)

    f32x4 acc[4][4];
    #pragma unroll
    for (int i = 0; i < 4; ++i)
        #pragma unroll
        for (int j = 0; j < 4; ++j)
            acc[i][j] = (f32x4){0.f, 0.f, 0.f, 0.f};

    // prologue: fill buffers 0,1,2 (12 DMA/thread in flight)
    ISSUE(0); ISSUE(1); ISSUE(2);

    #pragma unroll 4
    for (int ts = 0; ts < NSTEP; ++ts) {
        // S(ts) = oldest 4 of 12 outstanding -> vmcnt(8) retires it
        asm volatile("s_waitcnt vmcnt(8)" ::: "memory");
        __builtin_amdgcn_s_barrier();
        // refill the buffer read at step ts-1 (safe: barrier passed)
        const int nxt = (ts + 3 < NSTEP) ? ts + 3 : NSTEP - 1;
        ISSUE(nxt);

        const _Float16* ab = smem_h + (ts & 3) * BUF_H;
        const _Float16* bb = ab + 4096;
        f16x8 af[4], bf[4];
        #pragma unroll
        for (int mt = 0; mt < 4; ++mt)
            af[mt] = *(const f16x8*)(ab + (wr * 64 + mt * 16 + lr) * 32 + lk * 8);
        #pragma unroll
        for (int nt2 = 0; nt2 < 4; ++nt2)
            bf[nt2] = *(const f16x8*)(bb + (wc * 64 + nt2 * 16 + lr) * 32 + lk * 8);
        __builtin_amdgcn_s_setprio(1);
        #pragma unroll
        for (int mt = 0; mt < 4; ++mt)
            #pragma unroll
            for (int nt2 = 0; nt2 < 4; ++nt2)
                acc[mt][nt2] = __builtin_amdgcn_mfma_f32_16x16x32_f16(
                    af[mt], bf[nt2], acc[mt][nt2], 0, 0, 0);
        __builtin_amdgcn_s_setprio(0);
    }
    #undef ISSUE
    asm volatile("s_waitcnt vmcnt(0)" ::: "memory");

    // epilogue: D col (N=px) = lane&15; D row (M=c) = (lane>>4)*4 + reg
    const float scale = 0.25f * alphap[0];
    #pragma unroll
    for (int mt = 0; mt < 4; ++mt) {
        #pragma unroll
        for (int nt2 = 0; nt2 < 4; ++nt2) {
            #pragma unroll
            for (int r2 = 0; r2 < 4; ++r2) {
                int c  = c0 + wr * 64 + mt * 16 + lk * 4 + r2;
                int px = px0 + wc * 64 + nt2 * 16 + lr;
                int hh = px >> 5, ww2 = px & 31;
                int h = 2 * hh + ph, wp = 2 * ww2 + pw;
                size_t idx = (((size_t)b * CC + c) * HH + h) * WW + wp;
                out[idx] = orix[idx] + scale * acc[mt][nt2][r2];
            }
        }
    }
}

// ===========================================================================
// FALLBACK PATH (round-1 kernels, used only if ws too small)
// ===========================================================================
#define TILE_M 64
#define TILE_N 64
#define TILE_K 16

__global__ void copy_kernel(const float* __restrict__ src,
                            float* __restrict__ dst, int n4) {
    int i = blockIdx.x * blockDim.x + threadIdx.x;
    if (i < n4)
        reinterpret_cast<float4*>(dst)[i] =
            reinterpret_cast<const float4*>(src)[i];
}

__global__ void transpose_kernel(const float* __restrict__ x,
                                 float* __restrict__ xT) {
    __shared__ float tile[32][33];
    int bh = blockIdx.z;
    int b = bh >> 6, h = bh & 63;
    int c0 = blockIdx.y * 32, w0 = blockIdx.x * 32;
    int tw = threadIdx.x & 31;
    int tc = threadIdx.x >> 5;
    #pragma unroll
    for (int i = 0; i < 4; ++i) {
        int c = tc + i * 8;
        tile[c][tw] = x[(((size_t)b * CC + c0 + c) * HH + h) * WW + w0 + tw];
    }
    __syncthreads();
    int tcw = threadIdx.x & 31;
    int twr = threadIdx.x >> 5;
    #pragma unroll
    for (int i = 0; i < 4; ++i) {
        int w = twr + i * 8;
        xT[(((size_t)b * HH + h) * WW + w0 + w) * CC + c0 + tcw] = tile[tcw][w];
    }
}

__global__ __launch_bounds__(256)
void pgemm_scatter(const float* __restrict__ scores,
                   const float* __restrict__ xT,
                   const float* __restrict__ x,
                   const float* __restrict__ alpha,
                   float* __restrict__ out,
                   int use_xt) {
    __shared__ float As[TILE_K][TILE_M];
    __shared__ float Bs[TILE_K][TILE_N];

    const int b      = blockIdx.z;
    const int tile_n = blockIdx.x;
    const int m0     = blockIdx.y * TILE_M;
    const int uv     = tile_n >> 2;
    const int u      = uv >> 2, v = uv & 3;
    const int c0     = (tile_n & 3) * 64;

    const int t  = threadIdx.x;
    const int tx = t & 15;
    const int ty = t >> 4;

    float acc[4][4] = {};
    const float* sb = scores + (size_t)b * QRN * KN;

    for (int k0 = 0; k0 < KN; k0 += TILE_K) {
        {
            int mr = t >> 2;
            int kc = (t & 3) * 4;
            float4 av = *reinterpret_cast<const float4*>(
                sb + (size_t)(m0 + mr) * KN + k0 + kc);
            As[kc + 0][mr] = av.x;
            As[kc + 1][mr] = av.y;
            As[kc + 2][mr] = av.z;
            As[kc + 3][mr] = av.w;
        }
        {
            int kr = t >> 4;
            int kg = k0 + kr;
            int m  = kg >> 5, n = kg & 31;
            int rr = 2 * m + u - 1; rr = min(max(rr, 0), HH - 1);
            int cc = 2 * n + v - 1; cc = min(max(cc, 0), WW - 1);
            int ccol = (t & 15) * 4;
            if (use_xt) {
                float4 bv = *reinterpret_cast<const float4*>(
                    xT + ((((size_t)b * HH + rr) * WW + cc) * CC) + c0 + ccol);
                Bs[kr][ccol + 0] = bv.x;
                Bs[kr][ccol + 1] = bv.y;
                Bs[kr][ccol + 2] = bv.z;
                Bs[kr][ccol + 3] = bv.w;
            } else {
                #pragma unroll
                for (int j = 0; j < 4; ++j) {
                    int c = c0 + ccol + j;
                    Bs[kr][ccol + j] =
                        x[(((size_t)b * CC + c) * HH + rr) * WW + cc];
                }
            }
        }
        __syncthreads();

        #pragma unroll
        for (int k = 0; k < TILE_K; ++k) {
            float a4[4], b4[4];
            *reinterpret_cast<float4*>(a4) =
                *reinterpret_cast<const float4*>(&As[k][ty * 4]);
            *reinterpret_cast<float4*>(b4) =
                *reinterpret_cast<const float4*>(&Bs[k][tx * 4]);
            #pragma unroll
            for (int i = 0; i < 4; ++i)
                #pragma unroll
                for (int j = 0; j < 4; ++j)
                    acc[i][j] += a4[i] * b4[j];
        }
        __syncthreads();
    }

    const float scale = alpha[0] * 0.25f;
    #pragma unroll
    for (int i = 0; i < 4; ++i) {
        int qr = m0 + ty * 4 + i;
        int Q = qr >> 5, R = qr & 31;
        int h = 2 * Q + u - 1;
        int w = 2 * R + v - 1;
        if (h < 0 || h >= HH || w < 0 || w >= WW) continue;
        #pragma unroll
        for (int j = 0; j < 4; ++j) {
            int c = c0 + tx * 4 + j;
            atomicAdd(&out[(((size_t)b * CC + c) * HH + h) * WW + w],
                      acc[i][j] * scale);
        }
    }
}

// ===========================================================================
extern "C" void kernel_launch(void* const* d_in, const int* in_sizes, int n_in,
                              void* d_out, int out_size, void* d_ws,
                              size_t ws_size, hipStream_t stream) {
    const float* ori_x  = (const float*)d_in[0];
    const float* scores = (const float*)d_in[1];
    const float* alpha  = (const float*)d_in[2];
    float* out = (float*)d_out;

    const size_t need_fast = (TP_ELEMS + BP_ELEMS) * sizeof(_Float16);

    if (ws_size >= need_fast) {
        _Float16* T  = (_Float16*)d_ws;
        _Float16* Bp = T + TP_ELEMS;

        build_TB<<<dim3(TB_NWG), 256, 0, stream>>>(scores, ori_x, T, Bp);
        gemm_f16<<<dim3(2, 8, 16), 256, 0, stream>>>(T, Bp, ori_x, alpha, out);
    } else {
        float* xT = (float*)d_ws;
        const size_t xt_bytes = (size_t)BB * HH * WW * CC * sizeof(float);
        const int use_xt = (ws_size >= xt_bytes) ? 1 : 0;

        copy_kernel<<<(BB * CC * HH * WW / 4 + 255) / 256, 256, 0, stream>>>(
            ori_x, out, BB * CC * HH * WW / 4);
        if (use_xt)
            transpose_kernel<<<dim3(WW / 32, CC / 32, BB * HH), 256, 0,
                               stream>>>(ori_x, xT);
        pgemm_scatter<<<dim3(16, 16, BB), 256, 0, stream>>>(
            scores, xT, ori_x, alpha, out, use_xt);
    }
}

// Round 17
// 45.920 us; speedup vs baseline: 1.4196x; 1.0136x over previous
//
#include <hip/hip_runtime.h>
#include <hip/hip_bf16.h>
#include <hip/hip_fp16.h>

// Problem constants (B=4, C=256, H=W=64, hs=ws=32, rate=2, vk=4, pad=1)
#define BB 4
#define CC 256
#define HH 64
#define WW 64
#define QRN 1024
#define KN  1024
#define KDIM 1152            // 33*33 = 1089 padded to 36*32
#define TROWS 1089           // 33*33 combined-score rows per b

typedef _Float16 f16x8 __attribute__((ext_vector_type(8)));
typedef float f32x4 __attribute__((ext_vector_type(4)));

#define TP_ELEMS ((size_t)BB * TROWS * KDIM)   // 5,018,112 halves (10.0 MB)
#define BP_ELEMS ((size_t)16 * CC * KDIM)      // 4,718,592 halves (9.4 MB)

// ===========================================================================
// FAST PATH
// ===========================================================================

// One qr row of the combined-score tensor T (all 1152 k, 5 chunks/thread).
// T[b][qr=Qa*33+Ra][k=(mp,np)] =
//   sum_{dq,dr in {0,1}} [masks] s[b][(Qa-dq)*32+(Ra-dr)][(mp-dq)*32+(np-dr)]
// Pad region k>=1089 -> all masks false -> 0 (required: gemm multiplies it).
__device__ __forceinline__
void process_qr(const float* __restrict__ sb, _Float16* __restrict__ T,
                int b, int qr, int t) {
    const int Qa = (qr * 993) >> 15;        // qr/33 (exact for qr<2048)
    const int Ra = qr - 33 * Qa;
    const bool q0 = (Qa < 32), q1 = (Qa >= 1);        // block-uniform
    const bool r0 = (Ra < 32), r1 = (Ra >= 1);        // block-uniform
    const float* rb00 = sb + ((size_t)((Qa)     * 32 + (Ra)))     * KN;
    const float* rb01 = sb + ((size_t)((Qa)     * 32 + (Ra - 1))) * KN;
    const float* rb10 = sb + ((size_t)((Qa - 1) * 32 + (Ra)))     * KN;
    const float* rb11 = sb + ((size_t)((Qa - 1) * 32 + (Ra - 1))) * KN;
    _Float16* trow = T + ((size_t)b * TROWS + qr) * KDIM;

    float v[5];
    #pragma unroll
    for (int j = 0; j < 5; ++j) {
        const int k = j * 256 + t;
        v[j] = 0.f;
        if (k < KDIM) {
            const int mp = (k * 993) >> 15;  // k/33 (exact for k<2048)
            const int np = k - 33 * mp;
            const bool m0 = (mp < 32), m1 = (mp >= 1) && (mp < 33);
            const bool n0 = (np < 32), n1 = (np >= 1);
            const int col = (mp << 5) + np;
            if (q0 & r0 & m0 & n0) v[j] += rb00[col];
            if (q0 & r1 & m0 & n1) v[j] += rb01[col - 1];
            if (q1 & r0 & m1 & n0) v[j] += rb10[col - 32];
            if (q1 & r1 & m1 & n1) v[j] += rb11[col - 33];
        }
    }
    #pragma unroll
    for (int j = 0; j < 5; ++j) {
        const int k = j * 256 + t;
        if (k < KDIM) trow[k] = (_Float16)v[j];
    }
}

// Merged builder: T part (2 qr rows per block) + B part (x gather).
// Bijective XCD-chunk swizzle keeps all shifted readers of each scores
// element on one XCD's L2.
#define T_BLOCKS 545
#define PER_B    705
#define TB_NWG   (BB * PER_B)    // 2820

__global__ __launch_bounds__(256)
void build_TB(const float* __restrict__ s, const float* __restrict__ x,
              _Float16* __restrict__ T, _Float16* __restrict__ Bp) {
    // bijective XCD chunk remap (m204 form; nwg % 8 = 4)
    const int orig = blockIdx.x;
    const int xcd = orig & 7, pos = orig >> 3;
    const int q = TB_NWG / 8, r = TB_NWG % 8;            // 352, 4
    const int wgid =
        (xcd < r ? xcd * (q + 1) : r * (q + 1) + (xcd - r) * q) + pos;

    const int b = wgid / PER_B;
    const int rem = wgid - b * PER_B;
    const int t = threadIdx.x;

    if (rem < T_BLOCKS) {
        const float* sb = s + (size_t)b * QRN * KN;
        const int qr0 = rem * 2;
        process_qr(sb, T, b, qr0, t);
        if (qr0 + 1 < TROWS) process_qr(sb, T, b, qr0 + 1, t);
    } else {
        // ---------------- B part: Bp[bc][c][k] = gathered x ---------------
        const int u = rem - T_BLOCKS;           // [0,160)
        const int rest = u / 5;
        const int kc = u - rest * 5;
        const int cls = rest >> 3, cg = rest & 7;
        const int k = kc * 256 + t;
        if (k >= KDIM) return;
        const int ph = cls >> 1, pw = cls & 1;
        const int ua = 1 - ph, va = 1 - pw;
        const int bc = b * 4 + cls;

        const int mp = (k * 993) >> 15;
        const int np = k - 33 * mp;
        int rr = 2 * mp + ua - 1; rr = min(max(rr, 0), HH - 1);
        int cc2 = 2 * np + va - 1; cc2 = min(max(cc2, 0), WW - 1);
        const int off = rr * WW + cc2;

        const float* xb = x + ((size_t)b * CC + cg * 32) * HH * WW;
        _Float16* bpb = Bp + ((size_t)bc * CC + cg * 32) * KDIM + k;

        #pragma unroll 8
        for (int i = 0; i < 32; ++i) {
            bpb[(size_t)i * KDIM] = (_Float16)xb[(size_t)i * HH * WW + off];
        }
    }
}

// Direct global->LDS DMA (16 B per lane).
__device__ __forceinline__ void gload16(const _Float16* g, _Float16* l) {
    __builtin_amdgcn_global_load_lds(
        (const __attribute__((address_space(1))) unsigned int*)g,
        (__attribute__((address_space(3))) unsigned int*)l, 16, 0, 0);
}

// GEMM per (b,class): D[c][px] = sum_k Bp[c][k] * T[b][trow(px,cls)][k]
// m97 geometry: tile 128(c) x 128(px), 256 blocks (1/CU), 4 waves = 2x2
// quadrants of 64x64, BK=32, 36 steps, mfma_f32_16x16x32_f16 (16 MFMA : 8
// ds_read_b128 per wave-step). T3/T4 deep ring: global_load_lds staging
// (4 DMA/thread/step) into an 8-deep LDS ring (8 x 16 KB = 128 KB,
// [row][32k] layout = DMA-linear), 7-set lookahead (~540 cy, covers HBM
// latency), counted s_waitcnt vmcnt(24) - steady state 28 DMAs in flight,
// each wait retires exactly the set being consumed. One barrier per step,
// no ds_writes, no register staging. Tail re-issues set 35 (identical
// bytes - benign). Epilogue: out = ori_x + 0.25*alpha*D.
#define NSTEP  36                // KDIM/32
#define BUF_H  8192              // halves per ring buffer (A 4096 | B 4096)
__global__ __launch_bounds__(256, 1)
void gemm_f16(const _Float16* __restrict__ T,    // [4][1089][1152] (px side)
              const _Float16* __restrict__ Bp,   // [16][256][1152] (c side)
              const float* __restrict__ orix,
              const float* __restrict__ alphap,
              float* __restrict__ out) {
    __shared__ __align__(16) _Float16 smem_h[8 * BUF_H];   // 128 KB

    // XCD-grouping remap: XCD r gets 32 consecutive wids = 2 bc panels
    // (same b per XCD; complementary-pw classes share out/orix lines).
    const int lin = blockIdx.x + 2 * (blockIdx.y + 8 * blockIdx.z); // 0..255
    const int wid = (lin & 7) * 32 + (lin >> 3);
    const int bc  = wid >> 4;
    const int byy = (wid >> 1) & 7;
    const int bxx = wid & 1;

    const int b = bc >> 2, cls = bc & 3;
    const int ph = cls >> 1, pw = cls & 1;
    const int c0  = bxx * 128;
    const int px0 = byy * 128;

    const int t = threadIdx.x;
    const int wv = t >> 6, l = t & 63;
    const int lr = l & 15;                // 16x16 row/col within fragment
    const int lk = l >> 4;                // k-octet selector (8 halves)
    const int wr = wv >> 1, wc = wv & 1;  // wave quadrant (2x2 over 128x128)

    const _Float16* Ag = Bp + ((size_t)bc * CC + c0) * KDIM;   // M operand
    const _Float16* Tg = T + (size_t)b * TROWS * KDIM;         // N operand

    // Staging (chunk id == r*256+t; LDS halfoff = chunk*8 -> [row][32k]):
    //   row = chunk>>2 (r=0: 0..63, r=1: 64..127), slot = chunk&3.
    const int st_row = t >> 2, st_slot = t & 3;
    const _Float16* srcA0 = Ag + (size_t)st_row * KDIM + st_slot * 8;
    const _Float16* srcA1 = Ag + (size_t)(st_row + 64) * KDIM + st_slot * 8;
    const int pxr0 = px0 + st_row, pxr1 = px0 + st_row + 64;
    const int trow0 = ((pxr0 >> 5) + ph) * 33 + (pxr0 & 31) + pw;
    const int trow1 = ((pxr1 >> 5) + ph) * 33 + (pxr1 & 31) + pw;
    const _Float16* srcB0 = Tg + (size_t)trow0 * KDIM + st_slot * 8;
    const _Float16* srcB1 = Tg + (size_t)trow1 * KDIM + st_slot * 8;
    _Float16* dst0 = smem_h + t * 8;          // chunk r=0
    _Float16* dst1 = smem_h + 2048 + t * 8;   // chunk r=1
    // B region lives at +4096 halves within each buffer.

    #define ISSUE(ts2)                                                     \
        do {                                                               \
            const int _bo = ((ts2) & 7) * BUF_H;                           \
            const int _k0 = (ts2) * 32;                                    \
            gload16(srcA0 + _k0, dst0 + _bo);                              \
            gload16(srcA1 + _k0, dst1 + _bo);                              \
            gload16(srcB0 + _k0, dst0 + _bo + 4096);                       \
            gload16(srcB1 + _k0, dst1 + _bo + 4096);                       \
        } while (0)

    f32x4 acc[4][4];
    #pragma unroll
    for (int i = 0; i < 4; ++i)
        #pragma unroll
        for (int j = 0; j < 4; ++j)
            acc[i][j] = (f32x4){0.f, 0.f, 0.f, 0.f};

    // prologue: fill buffers 0..6 (28 DMA/thread in flight)
    ISSUE(0); ISSUE(1); ISSUE(2); ISSUE(3); ISSUE(4); ISSUE(5); ISSUE(6);

    #pragma unroll
    for (int ts = 0; ts < NSTEP; ++ts) {
        // invariant: 28 DMAs outstanding; oldest 4 = set ts -> vmcnt(24)
        asm volatile("s_waitcnt vmcnt(24)" ::: "memory");
        __builtin_amdgcn_s_barrier();
        // refill 7 steps ahead (buffer (ts+7)&7 != (ts)&7, conflict-free;
        // its previous readers finished at phase ts-1, fenced by barrier)
        const int nxt = (ts + 7 < NSTEP) ? ts + 7 : NSTEP - 1;
        ISSUE(nxt);

        const _Float16* ab = smem_h + (ts & 7) * BUF_H;
        const _Float16* bb = ab + 4096;
        f16x8 af[4], bf[4];
        #pragma unroll
        for (int mt = 0; mt < 4; ++mt)
            af[mt] = *(const f16x8*)(ab + (wr * 64 + mt * 16 + lr) * 32 + lk * 8);
        #pragma unroll
        for (int nt2 = 0; nt2 < 4; ++nt2)
            bf[nt2] = *(const f16x8*)(bb + (wc * 64 + nt2 * 16 + lr) * 32 + lk * 8);
        __builtin_amdgcn_s_setprio(1);
        #pragma unroll
        for (int mt = 0; mt < 4; ++mt)
            #pragma unroll
            for (int nt2 = 0; nt2 < 4; ++nt2)
                acc[mt][nt2] = __builtin_amdgcn_mfma_f32_16x16x32_f16(
                    af[mt], bf[nt2], acc[mt][nt2], 0, 0, 0);
        __builtin_amdgcn_s_setprio(0);
    }
    #undef ISSUE
    asm volatile("s_waitcnt vmcnt(0)" ::: "memory");

    // epilogue: D col (N=px) = lane&15; D row (M=c) = (lane>>4)*4 + reg
    const float scale = 0.25f * alphap[0];
    #pragma unroll
    for (int mt = 0; mt < 4; ++mt) {
        #pragma unroll
        for (int nt2 = 0; nt2 < 4; ++nt2) {
            #pragma unroll
            for (int r2 = 0; r2 < 4; ++r2) {
                int c  = c0 + wr * 64 + mt * 16 + lk * 4 + r2;
                int px = px0 + wc * 64 + nt2 * 16 + lr;
                int hh = px >> 5, ww2 = px & 31;
                int h = 2 * hh + ph, wp = 2 * ww2 + pw;
                size_t idx = (((size_t)b * CC + c) * HH + h) * WW + wp;
                out[idx] = orix[idx] + scale * acc[mt][nt2][r2];
            }
        }
    }
}

// ===========================================================================
// FALLBACK PATH (round-1 kernels, used only if ws too small)
// ===========================================================================
#define TILE_M 64
#define TILE_N 64
#define TILE_K 16

__global__ void copy_kernel(const float* __restrict__ src,
                            float* __restrict__ dst, int n4) {
    int i = blockIdx.x * blockDim.x + threadIdx.x;
    if (i < n4)
        reinterpret_cast<float4*>(dst)[i] =
            reinterpret_cast<const float4*>(src)[i];
}

__global__ void transpose_kernel(const float* __restrict__ x,
                                 float* __restrict__ xT) {
    __shared__ float tile[32][33];
    int bh = blockIdx.z;
    int b = bh >> 6, h = bh & 63;
    int c0 = blockIdx.y * 32, w0 = blockIdx.x * 32;
    int tw = threadIdx.x & 31;
    int tc = threadIdx.x >> 5;
    #pragma unroll
    for (int i = 0; i < 4; ++i) {
        int c = tc + i * 8;
        tile[c][tw] = x[(((size_t)b * CC + c0 + c) * HH + h) * WW + w0 + tw];
    }
    __syncthreads();
    int tcw = threadIdx.x & 31;
    int twr = threadIdx.x >> 5;
    #pragma unroll
    for (int i = 0; i < 4; ++i) {
        int w = twr + i * 8;
        xT[(((size_t)b * HH + h) * WW + w0 + w) * CC + c0 + tcw] = tile[tcw][w];
    }
}

__global__ __launch_bounds__(256)
void pgemm_scatter(const float* __restrict__ scores,
                   const float* __restrict__ xT,
                   const float* __restrict__ x,
                   const float* __restrict__ alpha,
                   float* __restrict__ out,
                   int use_xt) {
    __shared__ float As[TILE_K][TILE_M];
    __shared__ float Bs[TILE_K][TILE_N];

    const int b      = blockIdx.z;
    const int tile_n = blockIdx.x;
    const int m0     = blockIdx.y * TILE_M;
    const int uv     = tile_n >> 2;
    const int u      = uv >> 2, v = uv & 3;
    const int c0     = (tile_n & 3) * 64;

    const int t  = threadIdx.x;
    const int tx = t & 15;
    const int ty = t >> 4;

    float acc[4][4] = {};
    const float* sb = scores + (size_t)b * QRN * KN;

    for (int k0 = 0; k0 < KN; k0 += TILE_K) {
        {
            int mr = t >> 2;
            int kc = (t & 3) * 4;
            float4 av = *reinterpret_cast<const float4*>(
                sb + (size_t)(m0 + mr) * KN + k0 + kc);
            As[kc + 0][mr] = av.x;
            As[kc + 1][mr] = av.y;
            As[kc + 2][mr] = av.z;
            As[kc + 3][mr] = av.w;
        }
        {
            int kr = t >> 4;
            int kg = k0 + kr;
            int m  = kg >> 5, n = kg & 31;
            int rr = 2 * m + u - 1; rr = min(max(rr, 0), HH - 1);
            int cc = 2 * n + v - 1; cc = min(max(cc, 0), WW - 1);
            int ccol = (t & 15) * 4;
            if (use_xt) {
                float4 bv = *reinterpret_cast<const float4*>(
                    xT + ((((size_t)b * HH + rr) * WW + cc) * CC) + c0 + ccol);
                Bs[kr][ccol + 0] = bv.x;
                Bs[kr][ccol + 1] = bv.y;
                Bs[kr][ccol + 2] = bv.z;
                Bs[kr][ccol + 3] = bv.w;
            } else {
                #pragma unroll
                for (int j = 0; j < 4; ++j) {
                    int c = c0 + ccol + j;
                    Bs[kr][ccol + j] =
                        x[(((size_t)b * CC + c) * HH + rr) * WW + cc];
                }
            }
        }
        __syncthreads();

        #pragma unroll
        for (int k = 0; k < TILE_K; ++k) {
            float a4[4], b4[4];
            *reinterpret_cast<float4*>(a4) =
                *reinterpret_cast<const float4*>(&As[k][ty * 4]);
            *reinterpret_cast<float4*>(b4) =
                *reinterpret_cast<const float4*>(&Bs[k][tx * 4]);
            #pragma unroll
            for (int i = 0; i < 4; ++i)
                #pragma unroll
                for (int j = 0; j < 4; ++j)
                    acc[i][j] += a4[i] * b4[j];
        }
        __syncthreads();
    }

    const float scale = alpha[0] * 0.25f;
    #pragma unroll
    for (int i = 0; i < 4; ++i) {
        int qr = m0 + ty * 4 + i;
        int Q = qr >> 5, R = qr & 31;
        int h = 2 * Q + u - 1;
        int w = 2 * R + v - 1;
        if (h < 0 || h >= HH || w < 0 || w >= WW) continue;
        #pragma unroll
        for (int j = 0; j < 4; ++j) {
            int c = c0 + tx * 4 + j;
            atomicAdd(&out[(((size_t)b * CC + c) * HH + h) * WW + w],
                      acc[i][j] * scale);
        }
    }
}

// ===========================================================================
extern "C" void kernel_launch(void* const* d_in, const int* in_sizes, int n_in,
                              void* d_out, int out_size, void* d_ws,
                              size_t ws_size, hipStream_t stream) {
    const float* ori_x  = (const float*)d_in[0];
    const float* scores = (const float*)d_in[1];
    const float* alpha  = (const float*)d_in[2];
    float* out = (float*)d_out;

    const size_t need_fast = (TP_ELEMS + BP_ELEMS) * sizeof(_Float16);

    if (ws_size >= need_fast) {
        _Float16* T  = (_Float16*)d_ws;
        _Float16* Bp = T + TP_ELEMS;

        build_TB<<<dim3(TB_NWG), 256, 0, stream>>>(scores, ori_x, T, Bp);
        gemm_f16<<<dim3(2, 8, 16), 256, 0, stream>>>(T, Bp, ori_x, alpha, out);
    } else {
        float* xT = (float*)d_ws;
        const size_t xt_bytes = (size_t)BB * HH * WW * CC * sizeof(float);
        const int use_xt = (ws_size >= xt_bytes) ? 1 : 0;

        copy_kernel<<<(BB * CC * HH * WW / 4 + 255) / 256, 256, 0, stream>>>(
            ori_x, out, BB * CC * HH * WW / 4);
        if (use_xt)
            transpose_kernel<<<dim3(WW / 32, CC / 32, BB * HH), 256, 0,
                               stream>>>(ori_x, xT);
        pgemm_scatter<<<dim3(16, 16, BB), 256, 0, stream>>>(
            scores, xT, ori_x, alpha, out, use_xt);
    }
}